// Round 1
// baseline (202.874 us; speedup 1.0000x reference)
//
#include <hip/hip_runtime.h>

// Inverse SWT (db4, 3 levels), T=4096, circular boundary.
// One block per output row; running result lives in LDS, detail row staged in LDS.
// Per level: 8-tap windows are contiguous per 4 outputs -> vector ds_read_b128.

namespace {

constexpr int TT = 4096;       // time length
constexpr int T4 = TT / 4;     // in float4 units
constexpr int NT = 256;        // threads per block

template <int D, bool LAST>
__device__ __forceinline__ void iswt_level(const float4* __restrict__ gsrc,
                                           float* lds_res, float* lds_hi,
                                           float4* __restrict__ dst4, int t) {
  // db4 synthesis low-pass and QMF high-pass: hi[m] = (-1)^m * lo[7-m]
  constexpr float LO[8] = {
      0.23037781330885523f,  0.7148465705525415f,  0.6308807679295904f,
      -0.02798376941698385f, -0.18703481171888114f, 0.030841381835986965f,
      0.032883011666982945f, -0.010597401784997278f};
  constexpr float HI[8] = {
      -0.010597401784997278f, -0.032883011666982945f, 0.030841381835986965f,
      0.18703481171888114f,   -0.02798376941698385f,  -0.6308807679295904f,
      0.7148465705525415f,    -0.23037781330885523f};

  // Stage detail row into LDS (coalesced float4).
  float4* hiw4 = reinterpret_cast<float4*>(lds_hi);
#pragma unroll
  for (int k = 0; k < 4; ++k) hiw4[t + k * NT] = gsrc[t + k * NT];
  __syncthreads();

  // Window for 4 contiguous outputs n0..n0+3 at dilation D:
  // taps span [n0-4D, n0+3+3D] -> 7D+4 floats, 16B-aligned since n0 % 4 == 0.
  constexpr int W4 = (7 * D + 7) / 4;  // float4 count: D=4 -> 8, D=2 -> 5, D=1 -> 3
  const float4* res4 = reinterpret_cast<const float4*>(lds_res);
  const float4* hir4 = reinterpret_cast<const float4*>(lds_hi);

  float4 acc[4];
#pragma unroll
  for (int g = 0; g < 4; ++g) {
    const int c = t + g * NT;  // float4 chunk index, 0..1023 (lane-consecutive)
    float w[4 * W4];

    // --- approximation (res) contribution ---
#pragma unroll
    for (int i = 0; i < W4; ++i) {
      const float4 v = res4[(c - D + i) & (T4 - 1)];
      w[4 * i + 0] = v.x; w[4 * i + 1] = v.y;
      w[4 * i + 2] = v.z; w[4 * i + 3] = v.w;
    }
    float a0 = 0.f, a1 = 0.f, a2 = 0.f, a3 = 0.f;
#pragma unroll
    for (int m = 0; m < 8; ++m) {
      const int o = D * (7 - m);  // w[o+j] == res[n0 + j - D*(m-3)]
      a0 += LO[m] * w[o + 0];
      a1 += LO[m] * w[o + 1];
      a2 += LO[m] * w[o + 2];
      a3 += LO[m] * w[o + 3];
    }

    // --- detail (hi) contribution ---
#pragma unroll
    for (int i = 0; i < W4; ++i) {
      const float4 v = hir4[(c - D + i) & (T4 - 1)];
      w[4 * i + 0] = v.x; w[4 * i + 1] = v.y;
      w[4 * i + 2] = v.z; w[4 * i + 3] = v.w;
    }
#pragma unroll
    for (int m = 0; m < 8; ++m) {
      const int o = D * (7 - m);
      a0 += HI[m] * w[o + 0];
      a1 += HI[m] * w[o + 1];
      a2 += HI[m] * w[o + 2];
      a3 += HI[m] * w[o + 3];
    }
    acc[g] = make_float4(0.5f * a0, 0.5f * a1, 0.5f * a2, 0.5f * a3);
  }

  // All LDS reads done before overwriting res (or next level's hi staging).
  __syncthreads();
#pragma unroll
  for (int g = 0; g < 4; ++g) dst4[t + g * NT] = acc[g];
  if (!LAST) __syncthreads();
}

__global__ __launch_bounds__(NT) void iswt_kernel(const float* __restrict__ x,
                                                  float* __restrict__ out) {
  __shared__ __align__(16) float lds_res[TT];
  __shared__ __align__(16) float lds_hi[TT];

  const int t = threadIdx.x;
  const int row = blockIdx.x;  // r = b*64 + n; input rows 4r..4r+3 = cA3,cD3,cD2,cD1

  const float4* xr4 = reinterpret_cast<const float4*>(x) + (size_t)row * 4 * T4;
  float4* res4 = reinterpret_cast<float4*>(lds_res);

  // res = cA (level-3 approximation); sync is provided inside iswt_level.
#pragma unroll
  for (int k = 0; k < 4; ++k) res4[t + k * NT] = xr4[t + k * NT];

  iswt_level<4, false>(xr4 + 1 * T4, lds_res, lds_hi, res4, t);
  iswt_level<2, false>(xr4 + 2 * T4, lds_res, lds_hi, res4, t);
  float4* out4 = reinterpret_cast<float4*>(out) + (size_t)row * T4;
  iswt_level<1, true>(xr4 + 3 * T4, lds_res, lds_hi, out4, t);
}

}  // namespace

extern "C" void kernel_launch(void* const* d_in, const int* in_sizes, int n_in,
                              void* d_out, int out_size, void* d_ws, size_t ws_size,
                              hipStream_t stream) {
  const float* x = reinterpret_cast<const float*>(d_in[0]);
  float* out = reinterpret_cast<float*>(d_out);
  const int rows = out_size / TT;  // B*N = 2048
  iswt_kernel<<<rows, NT, 0, stream>>>(x, out);
}